// Round 2
// baseline (1085.329 us; speedup 1.0000x reference)
//
#include <hip/hip_runtime.h>
#include <hip/hip_fp16.h>

#define HS 1024
#define TT 2048

typedef _Float16 half8 __attribute__((ext_vector_type(8)));
typedef _Float16 half2t __attribute__((ext_vector_type(2)));
typedef __fp16 cvt2 __attribute__((ext_vector_type(2)));
typedef float floatx4 __attribute__((ext_vector_type(4)));

// K1: dproj[n*1024+a] = bias[a] + sum_e h_dec[n,e] * W[a, e]   (Wd = W[:, :1024])
__global__ __launch_bounds__(256) void k_dproj(const float* __restrict__ h_dec,
                                               const float* __restrict__ W,
                                               const float* __restrict__ bias,
                                               float* __restrict__ dproj) {
    int idx = blockIdx.x * 256 + threadIdx.x;   // 32768 threads
    int a = idx & 1023;
    int n = idx >> 10;
    const float4* hd = reinterpret_cast<const float4*>(h_dec + (size_t)n * HS);
    const float4* wr = reinterpret_cast<const float4*>(W + (size_t)a * 2048);
    float sx = 0.f, sy = 0.f, sz = 0.f, sw = 0.f;
    for (int i = 0; i < 256; ++i) {
        float4 h = hd[i]; float4 w = wr[i];
        sx += h.x * w.x; sy += h.y * w.y; sz += h.z * w.z; sw += h.w * w.w;
    }
    dproj[idx] = bias[a] + ((sx + sy) + (sz + sw));
}

// K2: We16[a*1024+e] = (fp16) W[a*2048 + 1024 + e]
__global__ __launch_bounds__(256) void k_cvtW(const float* __restrict__ W,
                                              _Float16* __restrict__ We16) {
    int idx4 = (blockIdx.x * 256 + threadIdx.x) * 4;  // 1M halves total
    int a = idx4 >> 10;
    int e = idx4 & 1023;
    float4 f = *reinterpret_cast<const float4*>(W + (size_t)a * 2048 + 1024 + e);
    half2t p0; p0[0] = (_Float16)f.x; p0[1] = (_Float16)f.y;
    half2t p1; p1[0] = (_Float16)f.z; p1[1] = (_Float16)f.w;
    *reinterpret_cast<half2t*>(We16 + idx4)     = p0;
    *reinterpret_cast<half2t*>(We16 + idx4 + 2) = p1;
}

// K3: fused score GEMM.  Per block: 128 t-rows of one n; loop 8 a-tiles of 128;
// K=1024 staged in BK=64 LDS tiles (h_enc cvt fp32->fp16 in flight, We16 direct).
// Epilogue per a-tile: score += v[a]*tanh(C + dproj[n,a]) reduced over a.
__global__ __launch_bounds__(256) void k_score(const float* __restrict__ h_enc,
                                               const _Float16* __restrict__ We16,
                                               const float* __restrict__ dproj,
                                               const float* __restrict__ v,
                                               float* __restrict__ scores) {
    __shared__ _Float16 As[128 * 64];   // [t_local][k] 16 KB
    __shared__ _Float16 Bs[128 * 64];   // [a_local][k] 16 KB
    __shared__ float s_acc[128];

    const int tid = threadIdx.x;
    const int n  = blockIdx.x >> 4;
    const int t0 = (blockIdx.x & 15) << 7;

    if (tid < 128) s_acc[tid] = 0.0f;

    const int wave = tid >> 6;
    const int lane = tid & 63;
    const int wm = wave >> 1, wn = wave & 1;     // 2x2 wave grid, each 64x64
    const int col = lane & 15, quad = lane >> 4;

    const int sr = tid >> 1;                 // staging row 0..127
    const int sc = (tid & 1) << 5;           // staging col offset 0/32 (elements)

    const float* gA0 = h_enc + ((size_t)(n * TT + t0 + sr)) * HS + sc;

    floatx4 acc[4][4];

    for (int pass = 0; pass < 8; ++pass) {
        const int a0 = pass << 7;

        float vv[4], dd[4];
#pragma unroll
        for (int ni = 0; ni < 4; ++ni) {
            int a = a0 + wn * 64 + ni * 16 + col;
            vv[ni] = v[a];
            dd[ni] = dproj[n * HS + a];
        }
#pragma unroll
        for (int mi = 0; mi < 4; ++mi)
#pragma unroll
            for (int ni = 0; ni < 4; ++ni)
                acc[mi][ni] = (floatx4)0.0f;

        for (int kk = 0; kk < HS; kk += 64) {
            // global loads first (overlap with barrier wait)
            float4 fa[8];
            const float4* gA = reinterpret_cast<const float4*>(gA0 + kk);
#pragma unroll
            for (int i = 0; i < 8; ++i) fa[i] = gA[i];
            uint4 fb[4];
            const uint4* gB = reinterpret_cast<const uint4*>(
                We16 + (size_t)(a0 + sr) * HS + kk + sc);
#pragma unroll
            for (int i = 0; i < 4; ++i) fb[i] = gB[i];

            __syncthreads();   // prev iter's ds_reads done before overwrite
#pragma unroll
            for (int i = 0; i < 4; ++i) {
                cvt2 p0 = __builtin_amdgcn_cvt_pkrtz(fa[2 * i].x, fa[2 * i].y);
                cvt2 p1 = __builtin_amdgcn_cvt_pkrtz(fa[2 * i].z, fa[2 * i].w);
                cvt2 p2 = __builtin_amdgcn_cvt_pkrtz(fa[2 * i + 1].x, fa[2 * i + 1].y);
                cvt2 p3 = __builtin_amdgcn_cvt_pkrtz(fa[2 * i + 1].z, fa[2 * i + 1].w);
                half8 h;
                h[0] = (_Float16)p0[0]; h[1] = (_Float16)p0[1];
                h[2] = (_Float16)p1[0]; h[3] = (_Float16)p1[1];
                h[4] = (_Float16)p2[0]; h[5] = (_Float16)p2[1];
                h[6] = (_Float16)p3[0]; h[7] = (_Float16)p3[1];
                *reinterpret_cast<half8*>(&As[sr * 64 + sc + i * 8]) = h;
            }
#pragma unroll
            for (int i = 0; i < 4; ++i)
                *reinterpret_cast<uint4*>(&Bs[sr * 64 + sc + i * 8]) = fb[i];
            __syncthreads();

            const half8* Af = reinterpret_cast<const half8*>(As);
            const half8* Bf = reinterpret_cast<const half8*>(Bs);
#pragma unroll
            for (int ko = 0; ko < 2; ++ko) {
                half8 af[4], bf[4];
#pragma unroll
                for (int mi = 0; mi < 4; ++mi)
                    af[mi] = Af[(wm * 64 + mi * 16 + col) * 8 + ko * 4 + quad];
#pragma unroll
                for (int ni = 0; ni < 4; ++ni)
                    bf[ni] = Bf[(wn * 64 + ni * 16 + col) * 8 + ko * 4 + quad];
#pragma unroll
                for (int mi = 0; mi < 4; ++mi)
#pragma unroll
                    for (int ni = 0; ni < 4; ++ni)
                        acc[mi][ni] = __builtin_amdgcn_mfma_f32_16x16x32_f16(
                            af[mi], bf[ni], acc[mi][ni], 0, 0, 0);
            }
        }

        // epilogue: s_acc[t] += sum_a v[a]*tanh(C[t][a] + dd[a])
        // C/D layout: col = lane&15 (a), row = quad*4+reg (t)
#pragma unroll
        for (int mi = 0; mi < 4; ++mi) {
#pragma unroll
            for (int rg = 0; rg < 4; ++rg) {
                float s = 0.0f;
#pragma unroll
                for (int ni = 0; ni < 4; ++ni) {
                    float x = acc[mi][ni][rg] + dd[ni];
                    float e2 = __expf(2.0f * x);
                    float th = 1.0f - 2.0f * __builtin_amdgcn_rcpf(e2 + 1.0f);
                    s += vv[ni] * th;
                }
                s += __shfl_xor(s, 8);
                s += __shfl_xor(s, 4);
                s += __shfl_xor(s, 2);
                s += __shfl_xor(s, 1);
                if (col == 0)
                    atomicAdd(&s_acc[wm * 64 + mi * 16 + quad * 4 + rg], s);
            }
        }
    }
    __syncthreads();
    if (tid < 128) scores[(size_t)n * TT + t0 + tid] = s_acc[tid];
}

// K4: masked softmax per row, in place on the weights region.
__global__ __launch_bounds__(256) void k_softmax(float* __restrict__ wout,
                                                 const int* __restrict__ lens) {
    __shared__ float red[4];
    __shared__ float red2[4];
    int n = blockIdx.x, tid = threadIdx.x;
    int len = lens[n];
    float* row = wout + (size_t)n * TT;
    float sv[8];
    float m = -3.0e38f;
#pragma unroll
    for (int i = 0; i < 8; ++i) {
        int t = tid + i * 256;
        float s = row[t];
        s = (t < len) ? s : -1.0e10f;
        sv[i] = s;
        m = fmaxf(m, s);
    }
    for (int off = 1; off <= 32; off <<= 1) m = fmaxf(m, __shfl_xor(m, off));
    if ((tid & 63) == 0) red[tid >> 6] = m;
    __syncthreads();
    m = fmaxf(fmaxf(red[0], red[1]), fmaxf(red[2], red[3]));
    float sum = 0.f, es[8];
#pragma unroll
    for (int i = 0; i < 8; ++i) { es[i] = __expf(sv[i] - m); sum += es[i]; }
    for (int off = 1; off <= 32; off <<= 1) sum += __shfl_xor(sum, off);
    if ((tid & 63) == 0) red2[tid >> 6] = sum;
    __syncthreads();
    sum = red2[0] + red2[1] + red2[2] + red2[3];
    float rinv = 1.0f / sum;
#pragma unroll
    for (int i = 0; i < 8; ++i) row[tid + i * 256] = es[i] * rinv;
}

// K5: ctx[n,e] = sum_t w[n,t] * h_enc[n,t,e]; 4-way t-split via atomics.
__global__ __launch_bounds__(256) void k_ctx(const float* __restrict__ h_enc,
                                             const float* __restrict__ wts,
                                             float* __restrict__ ctx) {
    __shared__ float4 red[256];
    int b = blockIdx.x;
    int n  = b >> 5;
    int ec = (b >> 2) & 7;
    int ts = b & 3;
    int tid = threadIdx.x;
    int q = tid & 31, tg = tid >> 5;
    int e = ec * 128 + q * 4;
    float4 acc = make_float4(0.f, 0.f, 0.f, 0.f);
    const float* wrow = wts + (size_t)n * TT;
    for (int t = ts * 512 + tg; t < ts * 512 + 512; t += 8) {
        float w = wrow[t];
        const float4 h = *reinterpret_cast<const float4*>(
            h_enc + ((size_t)(n * TT + t)) * HS + e);
        acc.x += w * h.x; acc.y += w * h.y; acc.z += w * h.z; acc.w += w * h.w;
    }
    red[tid] = acc;
    __syncthreads();
    if (tid < 32) {
        float4 s = red[tid];
        for (int g = 1; g < 8; ++g) {
            float4 r = red[g * 32 + tid];
            s.x += r.x; s.y += r.y; s.z += r.z; s.w += r.w;
        }
        float* dst = ctx + (size_t)n * HS + ec * 128 + tid * 4;
        atomicAdd(dst + 0, s.x);
        atomicAdd(dst + 1, s.y);
        atomicAdd(dst + 2, s.z);
        atomicAdd(dst + 3, s.w);
    }
}

extern "C" void kernel_launch(void* const* d_in, const int* in_sizes, int n_in,
                              void* d_out, int out_size, void* d_ws, size_t ws_size,
                              hipStream_t stream) {
    const float* h_dec   = (const float*)d_in[0];
    const float* h_enc   = (const float*)d_in[1];
    const int*   src_lens = (const int*)d_in[2];
    const float* W = (const float*)d_in[3];
    const float* b = (const float*)d_in[4];
    const float* v = (const float*)d_in[5];

    float* out = (float*)d_out;
    float* ctx = out;                 // 32*1024
    float* wts = out + 32 * 1024;     // 32*2048 (scores, then weights in place)

    float*    dproj = (float*)d_ws;                                    // 128 KB
    _Float16* We16  = (_Float16*)((char*)d_ws + 32 * 1024 * sizeof(float)); // 2 MB

    (void)hipMemsetAsync(ctx, 0, 32 * 1024 * sizeof(float), stream);
    k_dproj  <<<128,  256, 0, stream>>>(h_dec, W, b, dproj);
    k_cvtW   <<<1024, 256, 0, stream>>>(W, We16);
    k_score  <<<512,  256, 0, stream>>>(h_enc, We16, dproj, v, wts);
    k_softmax<<<32,   256, 0, stream>>>(wts, src_lens);
    k_ctx    <<<1024, 256, 0, stream>>>(h_enc, wts, ctx);
}

// Round 3
// 880.169 us; speedup vs baseline: 1.2331x; 1.2331x over previous
//
#include <hip/hip_runtime.h>
#include <hip/hip_fp16.h>

#define HS 1024
#define TT 2048
#define LDS_RS 72   // LDS row stride in halves: 64 + 8 pad (144 B = 9 granules)

typedef _Float16 half8 __attribute__((ext_vector_type(8)));
typedef float floatx4 __attribute__((ext_vector_type(4)));

// K1: dproj[n*1024+a] = bias[a] + sum_e h_dec[n,e] * W[a, e]   (Wd = W[:, :1024])
__global__ __launch_bounds__(256) void k_dproj(const float* __restrict__ h_dec,
                                               const float* __restrict__ W,
                                               const float* __restrict__ bias,
                                               float* __restrict__ dproj) {
    int idx = blockIdx.x * 256 + threadIdx.x;   // 32768 threads
    int a = idx & 1023;
    int n = idx >> 10;
    const float4* hd = reinterpret_cast<const float4*>(h_dec + (size_t)n * HS);
    const float4* wr = reinterpret_cast<const float4*>(W + (size_t)a * 2048);
    float sx = 0.f, sy = 0.f, sz = 0.f, sw = 0.f;
    for (int i = 0; i < 256; ++i) {
        float4 h = hd[i]; float4 w = wr[i];
        sx += h.x * w.x; sy += h.y * w.y; sz += h.z * w.z; sw += h.w * w.w;
    }
    dproj[idx] = bias[a] + ((sx + sy) + (sz + sw));
}

// K2: We16[a*1024+e] = (fp16) W[a*2048 + 1024 + e]  (RTN)
__global__ __launch_bounds__(256) void k_cvtW(const float* __restrict__ W,
                                              _Float16* __restrict__ We16) {
    int idx4 = (blockIdx.x * 256 + threadIdx.x) * 4;  // 1M halves total
    int a = idx4 >> 10;
    int e = idx4 & 1023;
    float4 f = *reinterpret_cast<const float4*>(W + (size_t)a * 2048 + 1024 + e);
    _Float16 h0 = (_Float16)f.x, h1 = (_Float16)f.y, h2 = (_Float16)f.z, h3 = (_Float16)f.w;
    ushort4 p;
    p.x = *(unsigned short*)&h0; p.y = *(unsigned short*)&h1;
    p.z = *(unsigned short*)&h2; p.w = *(unsigned short*)&h3;
    *reinterpret_cast<ushort4*>(We16 + idx4) = p;
}

// K2b: h_enc16 = (fp16) h_enc, streaming (RTN). 64M elements, 16/thread.
__global__ __launch_bounds__(256) void k_cvtA(const float* __restrict__ h_enc,
                                              _Float16* __restrict__ h_enc16) {
    size_t idx = ((size_t)blockIdx.x * 256 + threadIdx.x) * 16;
    const float4* g = reinterpret_cast<const float4*>(h_enc + idx);
    _Float16 h[16];
#pragma unroll
    for (int i = 0; i < 4; ++i) {
        float4 f = g[i];
        h[i * 4 + 0] = (_Float16)f.x; h[i * 4 + 1] = (_Float16)f.y;
        h[i * 4 + 2] = (_Float16)f.z; h[i * 4 + 3] = (_Float16)f.w;
    }
    *reinterpret_cast<uint4*>(h_enc16 + idx)     = *reinterpret_cast<uint4*>(&h[0]);
    *reinterpret_cast<uint4*>(h_enc16 + idx + 8) = *reinterpret_cast<uint4*>(&h[8]);
}

// K3: fused score GEMM. Block: 128 t-rows of one n; 4 a-passes of 256;
// K staged in BK=64 LDS tiles. Epilogue: score += v[a]*tanh(C + dproj) reduced over a.
template <bool AF16>
__global__ __launch_bounds__(256, 2) void k_score(const float* __restrict__ h_enc,
                                                  const _Float16* __restrict__ h_enc16,
                                                  const _Float16* __restrict__ We16,
                                                  const float* __restrict__ dproj,
                                                  const float* __restrict__ v,
                                                  float* __restrict__ scores) {
    __shared__ _Float16 As[128 * LDS_RS];   // 18.0 KB
    __shared__ _Float16 Bs[256 * LDS_RS];   // 36.0 KB
    __shared__ float s_acc[128];

    const int tid = threadIdx.x;
    const int n  = blockIdx.x >> 4;
    const int t0 = (blockIdx.x & 15) << 7;

    if (tid < 128) s_acc[tid] = 0.0f;

    const int wave = tid >> 6;
    const int lane = tid & 63;
    const int wm = wave >> 1, wn = wave & 1;     // waves 2x2; wave tile 64t x 128a
    const int col = lane & 15, quad = lane >> 4;

    const int srow = tid >> 2;                 // staging row within 64-row group
    const int sc   = (tid & 3) << 4;           // staging col offset 0/16/32/48 halves

    floatx4 acc[4][8];

    for (int pass = 0; pass < 4; ++pass) {
        const int a0 = pass << 8;

        float vv[8], dd[8];
#pragma unroll
        for (int ni = 0; ni < 8; ++ni) {
            int a = a0 + wn * 128 + ni * 16 + col;
            vv[ni] = v[a];
            dd[ni] = dproj[n * HS + a];
        }
#pragma unroll
        for (int mi = 0; mi < 4; ++mi)
#pragma unroll
            for (int ni = 0; ni < 8; ++ni)
                acc[mi][ni] = (floatx4)0.0f;

        for (int kk = 0; kk < HS; kk += 64) {
            // ---- global loads first (overlap with barrier wait) ----
            uint4  a16[2][2];
            float4 a32[2][4];
#pragma unroll
            for (int h = 0; h < 2; ++h) {
                const size_t row = (size_t)(n * TT + t0 + h * 64 + srow);
                if (AF16) {
                    const uint4* g = reinterpret_cast<const uint4*>(
                        h_enc16 + row * HS + kk + sc);
                    a16[h][0] = g[0]; a16[h][1] = g[1];
                } else {
                    const float4* g = reinterpret_cast<const float4*>(
                        h_enc + row * HS + kk + sc);
                    a32[h][0] = g[0]; a32[h][1] = g[1];
                    a32[h][2] = g[2]; a32[h][3] = g[3];
                }
            }
            uint4 b16[4][2];
#pragma unroll
            for (int h = 0; h < 4; ++h) {
                const uint4* g = reinterpret_cast<const uint4*>(
                    We16 + (size_t)(a0 + h * 64 + srow) * HS + kk + sc);
                b16[h][0] = g[0]; b16[h][1] = g[1];
            }

            __syncthreads();   // prev iter's ds_reads done before overwrite
#pragma unroll
            for (int h = 0; h < 2; ++h) {
                _Float16* dst = &As[(h * 64 + srow) * LDS_RS + sc];
                if (AF16) {
                    *reinterpret_cast<uint4*>(dst)     = a16[h][0];
                    *reinterpret_cast<uint4*>(dst + 8) = a16[h][1];
                } else {
                    _Float16 hv[16];
#pragma unroll
                    for (int i = 0; i < 4; ++i) {
                        float4 f = a32[h][i];
                        hv[i * 4 + 0] = (_Float16)f.x; hv[i * 4 + 1] = (_Float16)f.y;
                        hv[i * 4 + 2] = (_Float16)f.z; hv[i * 4 + 3] = (_Float16)f.w;
                    }
                    *reinterpret_cast<uint4*>(dst)     = *reinterpret_cast<uint4*>(&hv[0]);
                    *reinterpret_cast<uint4*>(dst + 8) = *reinterpret_cast<uint4*>(&hv[8]);
                }
            }
#pragma unroll
            for (int h = 0; h < 4; ++h) {
                _Float16* dst = &Bs[(h * 64 + srow) * LDS_RS + sc];
                *reinterpret_cast<uint4*>(dst)     = b16[h][0];
                *reinterpret_cast<uint4*>(dst + 8) = b16[h][1];
            }
            __syncthreads();

            // ---- MFMA on the 64-k tile ----
#pragma unroll
            for (int ko = 0; ko < 2; ++ko) {
                half8 af[4], bf[8];
#pragma unroll
                for (int mi = 0; mi < 4; ++mi)
                    af[mi] = *reinterpret_cast<const half8*>(
                        &As[(wm * 64 + mi * 16 + col) * LDS_RS + ko * 32 + quad * 8]);
#pragma unroll
                for (int ni = 0; ni < 8; ++ni)
                    bf[ni] = *reinterpret_cast<const half8*>(
                        &Bs[(wn * 128 + ni * 16 + col) * LDS_RS + ko * 32 + quad * 8]);
#pragma unroll
                for (int mi = 0; mi < 4; ++mi)
#pragma unroll
                    for (int ni = 0; ni < 8; ++ni)
                        acc[mi][ni] = __builtin_amdgcn_mfma_f32_16x16x32_f16(
                            af[mi], bf[ni], acc[mi][ni], 0, 0, 0);
            }
        }

        // epilogue: s_acc[t] += sum_a v[a]*tanh(C[t][a] + dd[a])
        // C/D layout: col = lane&15 (a), row = quad*4+reg (t)
#pragma unroll
        for (int mi = 0; mi < 4; ++mi) {
#pragma unroll
            for (int rg = 0; rg < 4; ++rg) {
                float s = 0.0f;
#pragma unroll
                for (int ni = 0; ni < 8; ++ni) {
                    float x = acc[mi][ni][rg] + dd[ni];
                    float e2 = __expf(2.0f * x);
                    float th = 1.0f - 2.0f * __builtin_amdgcn_rcpf(e2 + 1.0f);
                    s += vv[ni] * th;
                }
                s += __shfl_xor(s, 8);
                s += __shfl_xor(s, 4);
                s += __shfl_xor(s, 2);
                s += __shfl_xor(s, 1);
                if (col == 0)
                    atomicAdd(&s_acc[wm * 64 + mi * 16 + quad * 4 + rg], s);
            }
        }
    }
    __syncthreads();
    if (tid < 128) scores[(size_t)n * TT + t0 + tid] = s_acc[tid];
}

// K4: masked softmax per row, in place.
__global__ __launch_bounds__(256) void k_softmax(float* __restrict__ wout,
                                                 const int* __restrict__ lens) {
    __shared__ float red[4];
    __shared__ float red2[4];
    int n = blockIdx.x, tid = threadIdx.x;
    int len = lens[n];
    float* row = wout + (size_t)n * TT;
    float sv[8];
    float m = -3.0e38f;
#pragma unroll
    for (int i = 0; i < 8; ++i) {
        int t = tid + i * 256;
        float s = row[t];
        s = (t < len) ? s : -1.0e10f;
        sv[i] = s;
        m = fmaxf(m, s);
    }
    for (int off = 1; off <= 32; off <<= 1) m = fmaxf(m, __shfl_xor(m, off));
    if ((tid & 63) == 0) red[tid >> 6] = m;
    __syncthreads();
    m = fmaxf(fmaxf(red[0], red[1]), fmaxf(red[2], red[3]));
    float sum = 0.f, es[8];
#pragma unroll
    for (int i = 0; i < 8; ++i) { es[i] = __expf(sv[i] - m); sum += es[i]; }
    for (int off = 1; off <= 32; off <<= 1) sum += __shfl_xor(sum, off);
    if ((tid & 63) == 0) red2[tid >> 6] = sum;
    __syncthreads();
    sum = red2[0] + red2[1] + red2[2] + red2[3];
    float rinv = 1.0f / sum;
#pragma unroll
    for (int i = 0; i < 8; ++i) row[tid + i * 256] = es[i] * rinv;
}

// K5: ctx[n,e] = sum_t w[n,t] * h_enc[n,t,e]; t-split via atomics.
template <bool AF16>
__global__ __launch_bounds__(256) void k_ctx(const float* __restrict__ h_enc,
                                             const _Float16* __restrict__ h_enc16,
                                             const float* __restrict__ wts,
                                             float* __restrict__ ctx) {
    __shared__ float red[256][8];
    int b = blockIdx.x;               // 512 blocks: n(32) x ec(4) x ts(4)
    int n  = b >> 4;
    int ec = (b >> 2) & 3;
    int ts = b & 3;
    int tid = threadIdx.x;
    int q = tid & 31, tg = tid >> 5;
    int e = ec * 256 + q * 8;
    float acc[8];
#pragma unroll
    for (int j = 0; j < 8; ++j) acc[j] = 0.f;
    const float* wrow = wts + (size_t)n * TT;
    for (int t = ts * 512 + tg; t < ts * 512 + 512; t += 8) {
        float w = wrow[t];
        if (AF16) {
            uint4 raw = *reinterpret_cast<const uint4*>(
                h_enc16 + ((size_t)(n * TT + t)) * HS + e);
            const _Float16* hp = reinterpret_cast<const _Float16*>(&raw);
#pragma unroll
            for (int j = 0; j < 8; ++j) acc[j] += w * (float)hp[j];
        } else {
            const float4* gp = reinterpret_cast<const float4*>(
                h_enc + ((size_t)(n * TT + t)) * HS + e);
            float4 f0 = gp[0], f1 = gp[1];
            acc[0] += w * f0.x; acc[1] += w * f0.y; acc[2] += w * f0.z; acc[3] += w * f0.w;
            acc[4] += w * f1.x; acc[5] += w * f1.y; acc[6] += w * f1.z; acc[7] += w * f1.w;
        }
    }
#pragma unroll
    for (int j = 0; j < 8; ++j) red[tid][j] = acc[j];
    __syncthreads();
    if (tid < 32) {
        float s[8];
#pragma unroll
        for (int j = 0; j < 8; ++j) s[j] = red[tid][j];
        for (int g = 1; g < 8; ++g)
#pragma unroll
            for (int j = 0; j < 8; ++j) s[j] += red[g * 32 + tid][j];
        float* dst = ctx + (size_t)n * HS + ec * 256 + tid * 8;
#pragma unroll
        for (int j = 0; j < 8; ++j) atomicAdd(dst + j, s[j]);
    }
}

extern "C" void kernel_launch(void* const* d_in, const int* in_sizes, int n_in,
                              void* d_out, int out_size, void* d_ws, size_t ws_size,
                              hipStream_t stream) {
    const float* h_dec    = (const float*)d_in[0];
    const float* h_enc    = (const float*)d_in[1];
    const int*   src_lens = (const int*)d_in[2];
    const float* W = (const float*)d_in[3];
    const float* b = (const float*)d_in[4];
    const float* v = (const float*)d_in[5];

    float* out = (float*)d_out;
    float* ctx = out;                 // 32*1024
    float* wts = out + 32 * 1024;     // 32*2048 (scores, then weights in place)

    float*    dproj   = (float*)d_ws;                                  // 128 KB
    _Float16* We16    = (_Float16*)((char*)d_ws + 131072);             // 2 MB
    _Float16* h_enc16 = (_Float16*)((char*)d_ws + 131072 + 2097152);   // 128 MB
    const size_t need = 131072 + 2097152 + (size_t)32 * TT * HS * 2;
    const bool f16 = (ws_size >= need);

    (void)hipMemsetAsync(ctx, 0, 32 * 1024 * sizeof(float), stream);
    k_dproj<<<128, 256, 0, stream>>>(h_dec, W, b, dproj);
    k_cvtW <<<1024, 256, 0, stream>>>(W, We16);
    if (f16) {
        k_cvtA<<<16384, 256, 0, stream>>>(h_enc, h_enc16);
        k_score<true><<<512, 256, 0, stream>>>(h_enc, h_enc16, We16, dproj, v, wts);
        k_softmax<<<32, 256, 0, stream>>>(wts, src_lens);
        k_ctx<true><<<512, 256, 0, stream>>>(h_enc, h_enc16, wts, ctx);
    } else {
        k_score<false><<<512, 256, 0, stream>>>(h_enc, h_enc16, We16, dproj, v, wts);
        k_softmax<<<32, 256, 0, stream>>>(wts, src_lens);
        k_ctx<false><<<512, 256, 0, stream>>>(h_enc, h_enc16, wts, ctx);
    }
}

// Round 4
// 741.172 us; speedup vs baseline: 1.4643x; 1.1875x over previous
//
#include <hip/hip_runtime.h>
#include <hip/hip_fp16.h>

#define HS 1024
#define TT 2048

typedef _Float16 half8 __attribute__((ext_vector_type(8)));
typedef float floatx4 __attribute__((ext_vector_type(4)));

// Async global->LDS DMA, 16B per lane. LDS dest = wave-uniform base + lane*16.
__device__ __forceinline__ void dma16(const _Float16* g, _Float16* l) {
    __builtin_amdgcn_global_load_lds(
        (const __attribute__((address_space(1))) unsigned int*)g,
        (__attribute__((address_space(3))) unsigned int*)l, 16, 0, 0);
}

// K1: dproj[n*1024+a] = bias[a] + sum_e h_dec[n,e]*W[a,e]. One wave per (n,a),
// lanes stride e (coalesced 16B/lane), butterfly reduce.
__global__ __launch_bounds__(256) void k_dproj(const float* __restrict__ h_dec,
                                               const float* __restrict__ W,
                                               const float* __restrict__ bias,
                                               float* __restrict__ dproj) {
    int wid = blockIdx.x * 4 + (threadIdx.x >> 6);   // 0..32767
    int lane = threadIdx.x & 63;
    int n = wid >> 10, a = wid & 1023;
    const float4* hd = reinterpret_cast<const float4*>(h_dec + (size_t)n * HS);
    const float4* wr = reinterpret_cast<const float4*>(W + (size_t)a * 2048);
    float s = 0.f;
#pragma unroll
    for (int i = 0; i < 4; ++i) {
        float4 h = hd[lane + i * 64];
        float4 w = wr[lane + i * 64];
        s += h.x * w.x + h.y * w.y + h.z * w.z + h.w * w.w;
    }
    for (int off = 32; off; off >>= 1) s += __shfl_xor(s, off);
    if (lane == 0) dproj[wid] = bias[a] + s;
}

// K2: We16[a*1024+e] = (fp16) W[a*2048 + 1024 + e]
__global__ __launch_bounds__(256) void k_cvtW(const float* __restrict__ W,
                                              _Float16* __restrict__ We16) {
    int idx4 = (blockIdx.x * 256 + threadIdx.x) * 4;
    int a = idx4 >> 10;
    int e = idx4 & 1023;
    float4 f = *reinterpret_cast<const float4*>(W + (size_t)a * 2048 + 1024 + e);
    _Float16 h0 = (_Float16)f.x, h1 = (_Float16)f.y, h2 = (_Float16)f.z, h3 = (_Float16)f.w;
    ushort4 p;
    p.x = *(unsigned short*)&h0; p.y = *(unsigned short*)&h1;
    p.z = *(unsigned short*)&h2; p.w = *(unsigned short*)&h3;
    *reinterpret_cast<ushort4*>(We16 + idx4) = p;
}

// K2b: h_enc16 = (fp16) h_enc, streaming.
__global__ __launch_bounds__(256) void k_cvtA(const float* __restrict__ h_enc,
                                              _Float16* __restrict__ h_enc16) {
    size_t idx = ((size_t)blockIdx.x * 256 + threadIdx.x) * 16;
    const float4* g = reinterpret_cast<const float4*>(h_enc + idx);
    _Float16 h[16];
#pragma unroll
    for (int i = 0; i < 4; ++i) {
        float4 f = g[i];
        h[i * 4 + 0] = (_Float16)f.x; h[i * 4 + 1] = (_Float16)f.y;
        h[i * 4 + 2] = (_Float16)f.z; h[i * 4 + 3] = (_Float16)f.w;
    }
    *reinterpret_cast<uint4*>(h_enc16 + idx)     = *reinterpret_cast<uint4*>(&h[0]);
    *reinterpret_cast<uint4*>(h_enc16 + idx + 8) = *reinterpret_cast<uint4*>(&h[8]);
}

// K3: fused score GEMM, DMA-staged + double-buffered.
// Block: 128 t-rows of one n; flat loop over 4 a-passes x 16 k-iters (BK=64).
// LDS layout: row-major 64-half rows, 16B granule swizzle pg = g ^ (row&7).
// DMA(it+1) issued after barrier, in flight during 64 MFMAs of iter it.
__global__ __launch_bounds__(256, 2) void k_score(const _Float16* __restrict__ h_enc16,
                                                  const _Float16* __restrict__ We16,
                                                  const float* __restrict__ dproj,
                                                  const float* __restrict__ v,
                                                  float* __restrict__ scores) {
    __shared__ _Float16 Asb[2][128 * 64];   // 2 x 16 KB
    __shared__ _Float16 Bsb[2][256 * 64];   // 2 x 32 KB
    __shared__ float s_acc[128];

    const int tid = threadIdx.x;
    const int n  = blockIdx.x >> 4;
    const int t0 = (blockIdx.x & 15) << 7;

    if (tid < 128) s_acc[tid] = 0.0f;

    const int w    = tid >> 6;          // wave 0..3 (uniform)
    const int lane = tid & 63;
    const int wm = w >> 1, wn = w & 1;  // 2x2 wave grid; wave tile 64t x 128a
    const int col = lane & 15, quad = lane >> 4;

    // DMA source swizzle: lane -> (row_local = lane>>3, phys granule = lane&7),
    // logical column-chunk g = (lane&7) ^ row_local.
    const int lrow = lane >> 3;
    const int lg   = (lane & 7) ^ lrow;
    const size_t goff = (size_t)lrow * HS + lg * 8;   // halves

    const _Float16* gA = h_enc16 + (size_t)(n * TT + t0) * HS + goff;
    const _Float16* gB = We16 + goff;

    floatx4 acc[4][8];
    float vv[8], dd[8];

    // Issue the 12 DMA chunks (4 A + 8 B) for flat iteration `it` into buffer p.
    auto issue = [&](int it, int p) {
        const int a0 = (it >> 4) << 8;
        const int kk = (it & 15) << 6;
        const _Float16* gAi = gA + kk;
        const _Float16* gBi = gB + (size_t)a0 * HS + kk;
#pragma unroll
        for (int j = 0; j < 4; ++j)
            dma16(gAi + (size_t)(w * 32 + j * 8) * HS, &Asb[p][(w * 4 + j) * 512]);
#pragma unroll
        for (int j = 0; j < 8; ++j)
            dma16(gBi + (size_t)(w * 64 + j * 8) * HS, &Bsb[p][(w * 8 + j) * 512]);
    };

    issue(0, 0);

    for (int it = 0; it < 64; ++it) {
        const int p = it & 1;

        __syncthreads();   // drains vmcnt(0): DMA(it) landed; syncs all waves

        if (it + 1 < 64) issue(it + 1, 1 - p);

        if ((it & 15) == 0) {
            const int a0 = (it >> 4) << 8;
#pragma unroll
            for (int ni = 0; ni < 8; ++ni) {
                int a = a0 + wn * 128 + ni * 16 + col;
                vv[ni] = v[a];
                dd[ni] = dproj[n * HS + a];
            }
#pragma unroll
            for (int mi = 0; mi < 4; ++mi)
#pragma unroll
                for (int ni = 0; ni < 8; ++ni)
                    acc[mi][ni] = (floatx4)0.0f;
        }

        const _Float16* Ab = Asb[p];
        const _Float16* Bb = Bsb[p];
#pragma unroll
        for (int ko = 0; ko < 2; ++ko) {
            const int swz = ((ko * 4 + quad) ^ (col & 7)) * 8;
            half8 af[4], bf[8];
#pragma unroll
            for (int mi = 0; mi < 4; ++mi)
                af[mi] = *reinterpret_cast<const half8*>(
                    &Ab[(wm * 64 + mi * 16 + col) * 64 + swz]);
#pragma unroll
            for (int ni = 0; ni < 8; ++ni)
                bf[ni] = *reinterpret_cast<const half8*>(
                    &Bb[(wn * 128 + ni * 16 + col) * 64 + swz]);
#pragma unroll
            for (int mi = 0; mi < 4; ++mi)
#pragma unroll
                for (int ni = 0; ni < 8; ++ni)
                    acc[mi][ni] = __builtin_amdgcn_mfma_f32_16x16x32_f16(
                        af[mi], bf[ni], acc[mi][ni], 0, 0, 0);
        }

        if ((it & 15) == 15) {
            // epilogue: s_acc[t] += sum_a v[a]*tanh(C[t][a] + dd[a])
            // C/D layout: col = lane&15 (a), row = quad*4+reg (t)
#pragma unroll
            for (int mi = 0; mi < 4; ++mi) {
#pragma unroll
                for (int rg = 0; rg < 4; ++rg) {
                    float s = 0.0f;
#pragma unroll
                    for (int ni = 0; ni < 8; ++ni) {
                        float x = acc[mi][ni][rg] + dd[ni];
                        float e2 = __expf(2.0f * x);
                        float th = 1.0f - 2.0f * __builtin_amdgcn_rcpf(e2 + 1.0f);
                        s += vv[ni] * th;
                    }
                    s += __shfl_xor(s, 8);
                    s += __shfl_xor(s, 4);
                    s += __shfl_xor(s, 2);
                    s += __shfl_xor(s, 1);
                    if (col == 0)
                        atomicAdd(&s_acc[wm * 64 + mi * 16 + quad * 4 + rg], s);
                }
            }
        }
    }
    __syncthreads();
    if (tid < 128) scores[(size_t)n * TT + t0 + tid] = s_acc[tid];
}

// K4: masked softmax per row, in place.
__global__ __launch_bounds__(256) void k_softmax(float* __restrict__ wout,
                                                 const int* __restrict__ lens) {
    __shared__ float red[4];
    __shared__ float red2[4];
    int n = blockIdx.x, tid = threadIdx.x;
    int len = lens[n];
    float* row = wout + (size_t)n * TT;
    float sv[8];
    float m = -3.0e38f;
#pragma unroll
    for (int i = 0; i < 8; ++i) {
        int t = tid + i * 256;
        float s = row[t];
        s = (t < len) ? s : -1.0e10f;
        sv[i] = s;
        m = fmaxf(m, s);
    }
    for (int off = 1; off <= 32; off <<= 1) m = fmaxf(m, __shfl_xor(m, off));
    if ((tid & 63) == 0) red[tid >> 6] = m;
    __syncthreads();
    m = fmaxf(fmaxf(red[0], red[1]), fmaxf(red[2], red[3]));
    float sum = 0.f, es[8];
#pragma unroll
    for (int i = 0; i < 8; ++i) { es[i] = __expf(sv[i] - m); sum += es[i]; }
    for (int off = 1; off <= 32; off <<= 1) sum += __shfl_xor(sum, off);
    if ((tid & 63) == 0) red2[tid >> 6] = sum;
    __syncthreads();
    sum = red2[0] + red2[1] + red2[2] + red2[3];
    float rinv = 1.0f / sum;
#pragma unroll
    for (int i = 0; i < 8; ++i) row[tid + i * 256] = es[i] * rinv;
}

// K5: ctx[n,e] = sum_t w[n,t] * h_enc16[n,t,e]; t-split via atomics.
__global__ __launch_bounds__(256) void k_ctx(const _Float16* __restrict__ h_enc16,
                                             const float* __restrict__ wts,
                                             float* __restrict__ ctx) {
    __shared__ float red[256][8];
    int b = blockIdx.x;               // 512 blocks: n(32) x ec(4) x ts(4)
    int n  = b >> 4;
    int ec = (b >> 2) & 3;
    int ts = b & 3;
    int tid = threadIdx.x;
    int q = tid & 31, tg = tid >> 5;
    int e = ec * 256 + q * 8;
    float acc[8];
#pragma unroll
    for (int j = 0; j < 8; ++j) acc[j] = 0.f;
    const float* wrow = wts + (size_t)n * TT;
    for (int t = ts * 512 + tg; t < ts * 512 + 512; t += 8) {
        float w = wrow[t];
        uint4 raw = *reinterpret_cast<const uint4*>(
            h_enc16 + ((size_t)(n * TT + t)) * HS + e);
        const _Float16* hp = reinterpret_cast<const _Float16*>(&raw);
#pragma unroll
        for (int j = 0; j < 8; ++j) acc[j] += w * (float)hp[j];
    }
#pragma unroll
    for (int j = 0; j < 8; ++j) red[tid][j] = acc[j];
    __syncthreads();
    if (tid < 32) {
        float s[8];
#pragma unroll
        for (int j = 0; j < 8; ++j) s[j] = red[tid][j];
        for (int g = 1; g < 8; ++g)
#pragma unroll
            for (int j = 0; j < 8; ++j) s[j] += red[g * 32 + tid][j];
        float* dst = ctx + (size_t)n * HS + ec * 256 + tid * 8;
#pragma unroll
        for (int j = 0; j < 8; ++j) atomicAdd(dst + j, s[j]);
    }
}

// ---------- slow-but-correct fallback (only if ws is too small; unexpected) ----------
__global__ __launch_bounds__(256) void k_score_naive(const float* __restrict__ h_enc,
                                                     const float* __restrict__ W,
                                                     const float* __restrict__ dproj,
                                                     const float* __restrict__ v,
                                                     float* __restrict__ scores) {
    int gw = blockIdx.x * 4 + (threadIdx.x >> 6);   // wave per (n,t)
    int lane = threadIdx.x & 63;
    int n = gw >> 11, t = gw & 2047;
    const float4* he = reinterpret_cast<const float4*>(h_enc + ((size_t)(n * TT + t)) * HS);
    float4 hv[4];
#pragma unroll
    for (int i = 0; i < 4; ++i) hv[i] = he[lane + i * 64];
    float s = 0.f;
    for (int a = 0; a < 1024; ++a) {
        const float4* wr = reinterpret_cast<const float4*>(W + (size_t)a * 2048 + 1024);
        float d = 0.f;
#pragma unroll
        for (int i = 0; i < 4; ++i) {
            float4 wv = wr[lane + i * 64];
            d += hv[i].x * wv.x + hv[i].y * wv.y + hv[i].z * wv.z + hv[i].w * wv.w;
        }
        for (int off = 32; off; off >>= 1) d += __shfl_xor(d, off);
        s += v[a] * tanhf(d + dproj[n * HS + a]);
    }
    if (lane == 0) scores[(size_t)n * TT + t] = s;
}

__global__ __launch_bounds__(256) void k_ctx_naive(const float* __restrict__ h_enc,
                                                   const float* __restrict__ wts,
                                                   float* __restrict__ ctx) {
    int n = blockIdx.x;
    int e = threadIdx.x * 4;
    float4 a = make_float4(0.f, 0.f, 0.f, 0.f);
    const float* wrow = wts + (size_t)n * TT;
    for (int t = 0; t < TT; ++t) {
        float w = wrow[t];
        float4 h = *reinterpret_cast<const float4*>(h_enc + ((size_t)(n * TT + t)) * HS + e);
        a.x += w * h.x; a.y += w * h.y; a.z += w * h.z; a.w += w * h.w;
    }
    *reinterpret_cast<float4*>(ctx + (size_t)n * HS + e) = a;
}

extern "C" void kernel_launch(void* const* d_in, const int* in_sizes, int n_in,
                              void* d_out, int out_size, void* d_ws, size_t ws_size,
                              hipStream_t stream) {
    const float* h_dec    = (const float*)d_in[0];
    const float* h_enc    = (const float*)d_in[1];
    const int*   src_lens = (const int*)d_in[2];
    const float* W = (const float*)d_in[3];
    const float* b = (const float*)d_in[4];
    const float* v = (const float*)d_in[5];

    float* out = (float*)d_out;
    float* ctx = out;                 // 32*1024
    float* wts = out + 32 * 1024;     // 32*2048 (scores, then weights in place)

    float*    dproj   = (float*)d_ws;                                  // 128 KB
    _Float16* We16    = (_Float16*)((char*)d_ws + 131072);             // 2 MB
    _Float16* h_enc16 = (_Float16*)((char*)d_ws + 131072 + 2097152);   // 128 MB
    const size_t need = 131072 + 2097152 + (size_t)32 * TT * HS * 2;

    k_dproj<<<8192, 256, 0, stream>>>(h_dec, W, b, dproj);
    if (ws_size >= need) {
        (void)hipMemsetAsync(ctx, 0, 32 * 1024 * sizeof(float), stream);
        k_cvtW <<<1024, 256, 0, stream>>>(W, We16);
        k_cvtA <<<16384, 256, 0, stream>>>(h_enc, h_enc16);
        k_score<<<512, 256, 0, stream>>>(h_enc16, We16, dproj, v, wts);
        k_softmax<<<32, 256, 0, stream>>>(wts, src_lens);
        k_ctx  <<<512, 256, 0, stream>>>(h_enc16, wts, ctx);
    } else {
        k_score_naive<<<16384, 256, 0, stream>>>(h_enc, W, dproj, v, wts);
        k_softmax<<<32, 256, 0, stream>>>(wts, src_lens);
        k_ctx_naive<<<32, 256, 0, stream>>>(h_enc, wts, ctx);
    }
}

// Round 5
// 592.773 us; speedup vs baseline: 1.8309x; 1.2503x over previous
//
#include <hip/hip_runtime.h>
#include <hip/hip_fp16.h>

#define HS 1024
#define TT 2048

typedef _Float16 half8 __attribute__((ext_vector_type(8)));
typedef float floatx4 __attribute__((ext_vector_type(4)));

// Async global->LDS DMA, 16B per lane. LDS dest = wave-uniform base + lane*16.
__device__ __forceinline__ void dma16(const _Float16* g, _Float16* l) {
    __builtin_amdgcn_global_load_lds(
        (const __attribute__((address_space(1))) unsigned int*)g,
        (__attribute__((address_space(3))) unsigned int*)l, 16, 0, 0);
}

// K1: dproj[n*1024+a] = bias[a] + sum_e h_dec[n,e]*W[a,e]. One wave per (n,a).
__global__ __launch_bounds__(256) void k_dproj(const float* __restrict__ h_dec,
                                               const float* __restrict__ W,
                                               const float* __restrict__ bias,
                                               float* __restrict__ dproj) {
    int wid = blockIdx.x * 4 + (threadIdx.x >> 6);   // 0..32767
    int lane = threadIdx.x & 63;
    int n = wid >> 10, a = wid & 1023;
    const float4* hd = reinterpret_cast<const float4*>(h_dec + (size_t)n * HS);
    const float4* wr = reinterpret_cast<const float4*>(W + (size_t)a * 2048);
    float s = 0.f;
#pragma unroll
    for (int i = 0; i < 4; ++i) {
        float4 h = hd[lane + i * 64];
        float4 w = wr[lane + i * 64];
        s += h.x * w.x + h.y * w.y + h.z * w.z + h.w * w.w;
    }
    for (int off = 32; off; off >>= 1) s += __shfl_xor(s, off);
    if (lane == 0) dproj[wid] = bias[a] + s;
}

// K2: We16[a*1024+e] = (fp16) W[a*2048 + 1024 + e]
__global__ __launch_bounds__(256) void k_cvtW(const float* __restrict__ W,
                                              _Float16* __restrict__ We16) {
    int idx4 = (blockIdx.x * 256 + threadIdx.x) * 4;
    int a = idx4 >> 10;
    int e = idx4 & 1023;
    float4 f = *reinterpret_cast<const float4*>(W + (size_t)a * 2048 + 1024 + e);
    _Float16 h0 = (_Float16)f.x, h1 = (_Float16)f.y, h2 = (_Float16)f.z, h3 = (_Float16)f.w;
    ushort4 p;
    p.x = *(unsigned short*)&h0; p.y = *(unsigned short*)&h1;
    p.z = *(unsigned short*)&h2; p.w = *(unsigned short*)&h3;
    *reinterpret_cast<ushort4*>(We16 + idx4) = p;
}

// K2b: h_enc16 = (fp16) h_enc, streaming.
__global__ __launch_bounds__(256) void k_cvtA(const float* __restrict__ h_enc,
                                              _Float16* __restrict__ h_enc16) {
    size_t idx = ((size_t)blockIdx.x * 256 + threadIdx.x) * 16;
    const float4* g = reinterpret_cast<const float4*>(h_enc + idx);
    _Float16 h[16];
#pragma unroll
    for (int i = 0; i < 4; ++i) {
        float4 f = g[i];
        h[i * 4 + 0] = (_Float16)f.x; h[i * 4 + 1] = (_Float16)f.y;
        h[i * 4 + 2] = (_Float16)f.z; h[i * 4 + 3] = (_Float16)f.w;
    }
    *reinterpret_cast<uint4*>(h_enc16 + idx)     = *reinterpret_cast<uint4*>(&h[0]);
    *reinterpret_cast<uint4*>(h_enc16 + idx + 8) = *reinterpret_cast<uint4*>(&h[8]);
}

// K3: fused score GEMM, DMA-staged + double-buffered, BK=32 (48.5 KB LDS ->
// 2 blocks/CU, 2 waves/SIMD with 212 VGPR). Block: 128 t-rows of one n;
// flat loop: 4 a-passes x 32 k-iters. LDS rows of 32 halves (4 granules),
// granule swizzle pg = q ^ ((row>>1)&3) -> worst 2-way (free).
__global__ __launch_bounds__(256, 2) void k_score(const _Float16* __restrict__ h_enc16,
                                                  const _Float16* __restrict__ We16,
                                                  const float* __restrict__ dproj,
                                                  const float* __restrict__ v,
                                                  float* __restrict__ scores) {
    __shared__ _Float16 Asb[2][128 * 32];   // 2 x 8 KB
    __shared__ _Float16 Bsb[2][256 * 32];   // 2 x 16 KB
    __shared__ float s_acc[128];

    const int tid = threadIdx.x;
    const int n  = blockIdx.x >> 4;
    const int t0 = (blockIdx.x & 15) << 7;

    if (tid < 128) s_acc[tid] = 0.0f;

    const int w    = tid >> 6;          // wave 0..3 (uniform)
    const int lane = tid & 63;
    const int wm = w >> 1, wn = w & 1;  // 2x2 wave grid; wave tile 64t x 128a
    const int col = lane & 15, quad = lane >> 4;

    // DMA source mapping: one chunk = 16 rows x 32 halves (1 KB).
    // lane -> (lrow = lane>>2, phys granule = lane&3), logical granule
    // lg = (lane&3) ^ ((lrow>>1)&3).
    const int lrow = lane >> 2;
    const int lg   = (lane & 3) ^ ((lrow >> 1) & 3);
    const size_t goff = (size_t)lrow * HS + lg * 8;   // halves

    const _Float16* gA = h_enc16 + (size_t)(n * TT + t0) * HS + goff;
    const _Float16* gB = We16 + goff;

    floatx4 acc[4][8];
    float vv[8], dd[8];

    // Issue the 6 DMA chunks (2 A + 4 B) for flat iteration `it` into buffer p.
    auto issue = [&](int it, int p) {
        const int a0 = (it >> 5) << 8;
        const int kk = (it & 31) << 5;
        const _Float16* gAi = gA + kk;
        const _Float16* gBi = gB + (size_t)a0 * HS + kk;
#pragma unroll
        for (int j = 0; j < 2; ++j)
            dma16(gAi + (size_t)(w * 32 + j * 16) * HS, &Asb[p][(w * 2 + j) * 512]);
#pragma unroll
        for (int j = 0; j < 4; ++j)
            dma16(gBi + (size_t)(w * 64 + j * 16) * HS, &Bsb[p][(w * 4 + j) * 512]);
    };

    issue(0, 0);

    for (int it = 0; it < 128; ++it) {
        const int p = it & 1;

        __syncthreads();   // vmcnt(0) before barrier: DMA(it) landed

        if (it + 1 < 128) issue(it + 1, 1 - p);

        if ((it & 31) == 0) {
            const int a0 = (it >> 5) << 8;
#pragma unroll
            for (int ni = 0; ni < 8; ++ni) {
                int a = a0 + wn * 128 + ni * 16 + col;
                vv[ni] = v[a];
                dd[ni] = dproj[n * HS + a];
            }
#pragma unroll
            for (int mi = 0; mi < 4; ++mi)
#pragma unroll
                for (int ni = 0; ni < 8; ++ni)
                    acc[mi][ni] = (floatx4)0.0f;
        }

        const _Float16* Ab = Asb[p];
        const _Float16* Bb = Bsb[p];
        half8 af[4], bf[8];
#pragma unroll
        for (int mi = 0; mi < 4; ++mi) {
            const int r = wm * 64 + mi * 16 + col;
            af[mi] = *reinterpret_cast<const half8*>(
                &Ab[r * 32 + ((quad ^ ((r >> 1) & 3)) << 3)]);
        }
#pragma unroll
        for (int ni = 0; ni < 8; ++ni) {
            const int r = wn * 128 + ni * 16 + col;
            bf[ni] = *reinterpret_cast<const half8*>(
                &Bb[r * 32 + ((quad ^ ((r >> 1) & 3)) << 3)]);
        }
#pragma unroll
        for (int mi = 0; mi < 4; ++mi)
#pragma unroll
            for (int ni = 0; ni < 8; ++ni)
                acc[mi][ni] = __builtin_amdgcn_mfma_f32_16x16x32_f16(
                    af[mi], bf[ni], acc[mi][ni], 0, 0, 0);

        if ((it & 31) == 31) {
            // epilogue: s_acc[t] += sum_a v[a]*tanh(C[t][a] + dd[a])
            // C/D layout: col = lane&15 (a), row = quad*4+reg (t)
#pragma unroll
            for (int mi = 0; mi < 4; ++mi) {
#pragma unroll
                for (int rg = 0; rg < 4; ++rg) {
                    float s = 0.0f;
#pragma unroll
                    for (int ni = 0; ni < 8; ++ni) {
                        float x = acc[mi][ni][rg] + dd[ni];
                        float e2 = __expf(2.0f * x);
                        float th = 1.0f - 2.0f * __builtin_amdgcn_rcpf(e2 + 1.0f);
                        s += vv[ni] * th;
                    }
                    s += __shfl_xor(s, 8);
                    s += __shfl_xor(s, 4);
                    s += __shfl_xor(s, 2);
                    s += __shfl_xor(s, 1);
                    if (col == 0)
                        atomicAdd(&s_acc[wm * 64 + mi * 16 + quad * 4 + rg], s);
                }
            }
        }
    }
    __syncthreads();
    if (tid < 128) scores[(size_t)n * TT + t0 + tid] = s_acc[tid];
}

// K4: masked softmax per row, in place.
__global__ __launch_bounds__(256) void k_softmax(float* __restrict__ wout,
                                                 const int* __restrict__ lens) {
    __shared__ float red[4];
    __shared__ float red2[4];
    int n = blockIdx.x, tid = threadIdx.x;
    int len = lens[n];
    float* row = wout + (size_t)n * TT;
    float sv[8];
    float m = -3.0e38f;
#pragma unroll
    for (int i = 0; i < 8; ++i) {
        int t = tid + i * 256;
        float s = row[t];
        s = (t < len) ? s : -1.0e10f;
        sv[i] = s;
        m = fmaxf(m, s);
    }
    for (int off = 1; off <= 32; off <<= 1) m = fmaxf(m, __shfl_xor(m, off));
    if ((tid & 63) == 0) red[tid >> 6] = m;
    __syncthreads();
    m = fmaxf(fmaxf(red[0], red[1]), fmaxf(red[2], red[3]));
    float sum = 0.f, es[8];
#pragma unroll
    for (int i = 0; i < 8; ++i) { es[i] = __expf(sv[i] - m); sum += es[i]; }
    for (int off = 1; off <= 32; off <<= 1) sum += __shfl_xor(sum, off);
    if ((tid & 63) == 0) red2[tid >> 6] = sum;
    __syncthreads();
    sum = red2[0] + red2[1] + red2[2] + red2[3];
    float rinv = 1.0f / sum;
#pragma unroll
    for (int i = 0; i < 8; ++i) row[tid + i * 256] = es[i] * rinv;
}

// K5: ctx[n,e] = sum_t w[n,t] * h_enc16[n,t,e]; t-split via atomics.
__global__ __launch_bounds__(256) void k_ctx(const _Float16* __restrict__ h_enc16,
                                             const float* __restrict__ wts,
                                             float* __restrict__ ctx) {
    __shared__ float red[256][8];
    int b = blockIdx.x;               // 512 blocks: n(32) x ec(4) x ts(4)
    int n  = b >> 4;
    int ec = (b >> 2) & 3;
    int ts = b & 3;
    int tid = threadIdx.x;
    int q = tid & 31, tg = tid >> 5;
    int e = ec * 256 + q * 8;
    float acc[8];
#pragma unroll
    for (int j = 0; j < 8; ++j) acc[j] = 0.f;
    const float* wrow = wts + (size_t)n * TT;
    for (int t = ts * 512 + tg; t < ts * 512 + 512; t += 8) {
        float w = wrow[t];
        uint4 raw = *reinterpret_cast<const uint4*>(
            h_enc16 + ((size_t)(n * TT + t)) * HS + e);
        const _Float16* hp = reinterpret_cast<const _Float16*>(&raw);
#pragma unroll
        for (int j = 0; j < 8; ++j) acc[j] += w * (float)hp[j];
    }
#pragma unroll
    for (int j = 0; j < 8; ++j) red[tid][j] = acc[j];
    __syncthreads();
    if (tid < 32) {
        float s[8];
#pragma unroll
        for (int j = 0; j < 8; ++j) s[j] = red[tid][j];
        for (int g = 1; g < 8; ++g)
#pragma unroll
            for (int j = 0; j < 8; ++j) s[j] += red[g * 32 + tid][j];
        float* dst = ctx + (size_t)n * HS + ec * 256 + tid * 8;
#pragma unroll
        for (int j = 0; j < 8; ++j) atomicAdd(dst + j, s[j]);
    }
}

// ---------- slow-but-correct fallback (only if ws is too small; unexpected) ----------
__global__ __launch_bounds__(256) void k_score_naive(const float* __restrict__ h_enc,
                                                     const float* __restrict__ W,
                                                     const float* __restrict__ dproj,
                                                     const float* __restrict__ v,
                                                     float* __restrict__ scores) {
    int gw = blockIdx.x * 4 + (threadIdx.x >> 6);   // wave per (n,t)
    int lane = threadIdx.x & 63;
    int n = gw >> 11, t = gw & 2047;
    const float4* he = reinterpret_cast<const float4*>(h_enc + ((size_t)(n * TT + t)) * HS);
    float4 hv[4];
#pragma unroll
    for (int i = 0; i < 4; ++i) hv[i] = he[lane + i * 64];
    float s = 0.f;
    for (int a = 0; a < 1024; ++a) {
        const float4* wr = reinterpret_cast<const float4*>(W + (size_t)a * 2048 + 1024);
        float d = 0.f;
#pragma unroll
        for (int i = 0; i < 4; ++i) {
            float4 wv = wr[lane + i * 64];
            d += hv[i].x * wv.x + hv[i].y * wv.y + hv[i].z * wv.z + hv[i].w * wv.w;
        }
        for (int off = 32; off; off >>= 1) d += __shfl_xor(d, off);
        s += v[a] * tanhf(d + dproj[n * HS + a]);
    }
    if (lane == 0) scores[(size_t)n * TT + t] = s;
}

__global__ __launch_bounds__(256) void k_ctx_naive(const float* __restrict__ h_enc,
                                                   const float* __restrict__ wts,
                                                   float* __restrict__ ctx) {
    int n = blockIdx.x;
    int e = threadIdx.x * 4;
    float4 a = make_float4(0.f, 0.f, 0.f, 0.f);
    const float* wrow = wts + (size_t)n * TT;
    for (int t = 0; t < TT; ++t) {
        float w = wrow[t];
        float4 h = *reinterpret_cast<const float4*>(h_enc + ((size_t)(n * TT + t)) * HS + e);
        a.x += w * h.x; a.y += w * h.y; a.z += w * h.z; a.w += w * h.w;
    }
    *reinterpret_cast<float4*>(ctx + (size_t)n * HS + e) = a;
}

extern "C" void kernel_launch(void* const* d_in, const int* in_sizes, int n_in,
                              void* d_out, int out_size, void* d_ws, size_t ws_size,
                              hipStream_t stream) {
    const float* h_dec    = (const float*)d_in[0];
    const float* h_enc    = (const float*)d_in[1];
    const int*   src_lens = (const int*)d_in[2];
    const float* W = (const float*)d_in[3];
    const float* b = (const float*)d_in[4];
    const float* v = (const float*)d_in[5];

    float* out = (float*)d_out;
    float* ctx = out;                 // 32*1024
    float* wts = out + 32 * 1024;     // 32*2048 (scores, then weights in place)

    float*    dproj   = (float*)d_ws;                                  // 128 KB
    _Float16* We16    = (_Float16*)((char*)d_ws + 131072);             // 2 MB
    _Float16* h_enc16 = (_Float16*)((char*)d_ws + 131072 + 2097152);   // 128 MB
    const size_t need = 131072 + 2097152 + (size_t)32 * TT * HS * 2;

    k_dproj<<<8192, 256, 0, stream>>>(h_dec, W, b, dproj);
    if (ws_size >= need) {
        (void)hipMemsetAsync(ctx, 0, 32 * 1024 * sizeof(float), stream);
        k_cvtW <<<1024, 256, 0, stream>>>(W, We16);
        k_cvtA <<<16384, 256, 0, stream>>>(h_enc, h_enc16);
        k_score<<<512, 256, 0, stream>>>(h_enc16, We16, dproj, v, wts);
        k_softmax<<<32, 256, 0, stream>>>(wts, src_lens);
        k_ctx  <<<512, 256, 0, stream>>>(h_enc16, wts, ctx);
    } else {
        k_score_naive<<<16384, 256, 0, stream>>>(h_enc, W, dproj, v, wts);
        k_softmax<<<32, 256, 0, stream>>>(wts, src_lens);
        k_ctx_naive<<<32, 256, 0, stream>>>(h_enc, wts, ctx);
    }
}